// Round 28
// baseline (40.688 us; speedup 1.0000x reference)
//
#include <hip/hip_runtime.h>
#include <hip/hip_bf16.h>

// Depth-4 path signature, C=10, L=64, B=2048 — MFMA formulation (R28).
// Closed form (validated R8-R27, absmax 5.25 vs thr 12.16):
//   P_t = exclusive prefix of dx;  R_t[l] = S1[l] - P_{t+1}[l]
//   per (i,j): s2 serial chain; u2_t, v2_t level-2 scalars
//   S4[ij,kl] = sum_t v2_t*(dx_t[k]*R_t[l]) + sum_t u2_t*(dx_t[k]*dx_t[l]/2)
//   S3[ij,k]  = sum_t v2_t*dx_t[k]
// R28 vs R27 (best, 29.1us): PERSISTENT 2-ELEM BLOCKS. Grid 1024 = exactly
// 4 resident blocks/CU at launch (no second dispatch wave); each block loops
// over 2 consecutive elems. Safety: elem-2's stage writes only dxT/PsT/P1T,
// which elem-1's GEMM never reads -> iteration 2 starts the moment elem-1's
// GEMM issues its stores; elem-2's stage+scan+A-build overlap elem-1's 49KB
// store drain. bar1 of iter 2 orders the Ab/Ub rewrite after elem-1's GEMM
// reads. Per-elem FP sequence identical -> absmax must stay EXACTLY 5.25.

typedef short short8 __attribute__((ext_vector_type(8)));
typedef float f2 __attribute__((ext_vector_type(2)));
typedef float f4 __attribute__((ext_vector_type(4)));
typedef float f32x4 __attribute__((ext_vector_type(4)));
typedef unsigned int uint4v __attribute__((ext_vector_type(4)));

constexpr int C = 10, L = 64, T = 63;          // T = L-1 steps
constexpr int OUTSZ = 10 + 100 + 1000 + 10000; // 11110
constexpr int SP = 68;                         // dxT/PsT/P1T row stride (fp32)
constexpr int KS = 64;                         // A row stride in shorts (128B)

__device__ __forceinline__ unsigned packbf(float lo, float hi) {  // v_cvt_pk_bf16_f32
  union { __hip_bfloat162 h; unsigned u; } cv;
  cv.h = __float22bfloat162_rn(make_float2(lo, hi));
  return cv.u;
}
__device__ __forceinline__ int swz(int row, int k) {  // short idx, 16B-granule XOR
  return row * KS + ((((k >> 3) ^ (row & 7)) << 3) | (k & 7));
}
union frag_cast { uint4v u; short8 s; };

__global__ __launch_bounds__(512, 8) void sig4_kernel(
    const float* __restrict__ x, float* __restrict__ out)
{
  __shared__ __align__(16) unsigned char smem_raw[33760];
  unsigned short* Ab = (unsigned short*)smem_raw;            // V2: 12800B
  unsigned short* Ub = (unsigned short*)(smem_raw + 12800);  // U2: 12800B
  float* dxT = (float*)(smem_raw + 25600);                   // 10*68 f = 2720B
  float* PsT = (float*)(smem_raw + 28320);                   // 2720B
  float* P1T = (float*)(smem_raw + 31040);                   // 2720B (P[s+1])

  const int t = threadIdx.x;
  const int w = t >> 6, lane = t & 63;
  const int lm = lane & 15, lg = lane >> 4;

  #pragma unroll 1
  for (int it = 0; it < 2; ++it) {
    const size_t elem = (size_t)blockIdx.x * 2 + it;
    const float* __restrict__ xb = x + elem * (C * L);
    float* __restrict__ ob = out + elem * OUTSZ;

    // ---- merged stage+scan (writes dxT/PsT/P1T only — overlaps prev GEMM) ----
    for (int c = 7 - w; c < C; c += 8) {     // waves 6,7 take extra channels
      float xv = xb[c * L + lane];           // coalesced 256B per wave
      float xn = __shfl_down(xv, 1);         // x[lane+1]
      float dx = (lane < T) ? (xn - xv) : 0.f;
      dxT[c * SP + lane] = dx;
      float vprev = __shfl_up(dx, 1);        // dx[lane-1]
      float v = (lane > 0) ? vprev : 0.f;
      #pragma unroll
      for (int d = 1; d < 64; d <<= 1) {     // inclusive scan of shifted dx = excl
        float y = __shfl_up(v, d);
        if (lane >= d) v += y;
      }
      PsT[c * SP + lane] = v;                // P[lane]; PsT[63] = S1 (dx63=0)
      float p1 = __shfl_down(v, 1);          // P[lane+1]
      if (lane == 63) p1 = v;
      P1T[c * SP + lane] = p1;
    }
    __syncthreads();                         // also orders prev-iter GEMM reads

    // ---- A-build (t<100, serial s2 chain) ----
    if (t < 100) {
      const int i_ = t / 10, j_ = t - (t / 10) * 10;
      const float* dip = dxT + i_ * SP;
      const float* pp  = PsT + i_ * SP;
      const float* djp = dxT + j_ * SP;
      float s2 = 0.f;
      #pragma unroll
      for (int ch = 0; ch < 8; ++ch) {
        f4 d0 = *(const f4*)(dip + ch * 8), d1 = *(const f4*)(dip + ch * 8 + 4);
        f4 p0 = *(const f4*)(pp  + ch * 8), p1 = *(const f4*)(pp  + ch * 8 + 4);
        f4 e0 = *(const f4*)(djp + ch * 8), e1 = *(const f4*)(djp + ch * 8 + 4);
        float di[8] = {d0.x, d0.y, d0.z, d0.w, d1.x, d1.y, d1.z, d1.w};
        float pv[8] = {p0.x, p0.y, p0.z, p0.w, p1.x, p1.y, p1.z, p1.w};
        float dj[8] = {e0.x, e0.y, e0.z, e0.w, e1.x, e1.y, e1.z, e1.w};
        float bu[8], bv[8], zz[8];
        #pragma unroll
        for (int e = 0; e < 8; ++e) {          // pointwise (s=63: all zero)
          bu[e] = fmaf(di[e], 0.25f, pv[e]) * (dj[e] * (1.f / 3.f));
          bv[e] = fmaf(di[e], (1.f / 3.f), pv[e]) * (dj[e] * 0.5f);
          zz[e] = fmaf(di[e], 0.5f, pv[e]) * dj[e];
        }
        float u2v[8], v2v[8];
        #pragma unroll
        for (int e = 0; e < 8; ++e) {          // serial: 1 dependent add/step
          u2v[e] = bu[e] + s2;
          v2v[e] = bv[e] + s2;
          s2 += zz[e];
        }
        uint4v vp, up;
        #pragma unroll
        for (int q = 0; q < 4; ++q) {
          vp[q] = packbf(v2v[2 * q], v2v[2 * q + 1]);
          up[q] = packbf(u2v[2 * q], u2v[2 * q + 1]);
        }
        *(uint4v*)&Ab[swz(t, ch * 8)] = vp;
        *(uint4v*)&Ub[swz(t, ch * 8)] = up;
      }
      ob[10 + t] = s2;                         // S2 (fp32)
      if (j_ == 0) ob[i_] = PsT[i_ * SP + 63]; // S1
    }

    // ---- B-fragments (needs only dxT/PsT/P1T; concurrent with A-build) ----
    frag_cast B00, B01, B10, B11;
    B00.u = uint4v{0, 0, 0, 0}; B01.u = uint4v{0, 0, 0, 0};
    B10.u = uint4v{0, 0, 0, 0}; B11.u = uint4v{0, 0, 0, 0};
    if (w < 7) {
      const int bcol = w * 16 + lm;            // this lane's B column
      if (bcol < 100) {
        const int k2 = bcol / 10, l2 = bcol - (bcol / 10) * 10;
        const float* dk = dxT + k2 * SP;
        const float* dl = dxT + l2 * SP;
        const float* p1 = P1T + l2 * SP;
        const float S1l = PsT[l2 * SP + 63];
        f4 q0 = *(const f4*)(dk + lg * 8),      q1 = *(const f4*)(dk + lg * 8 + 4);
        f4 q2 = *(const f4*)(dk + 32 + lg * 8), q3 = *(const f4*)(dk + 32 + lg * 8 + 4);
        f4 r0 = *(const f4*)(p1 + lg * 8),      r1 = *(const f4*)(p1 + lg * 8 + 4);
        f4 r2 = *(const f4*)(p1 + 32 + lg * 8), r3 = *(const f4*)(p1 + 32 + lg * 8 + 4);
        f4 s0 = *(const f4*)(dl + lg * 8),      s1 = *(const f4*)(dl + lg * 8 + 4);
        f4 s2v = *(const f4*)(dl + 32 + lg * 8), s3 = *(const f4*)(dl + 32 + lg * 8 + 4);
        B00.u = uint4v{packbf(q0.x * (S1l - r0.x), q0.y * (S1l - r0.y)),
                       packbf(q0.z * (S1l - r0.z), q0.w * (S1l - r0.w)),
                       packbf(q1.x * (S1l - r1.x), q1.y * (S1l - r1.y)),
                       packbf(q1.z * (S1l - r1.z), q1.w * (S1l - r1.w))};
        B01.u = uint4v{packbf(q2.x * (S1l - r2.x), q2.y * (S1l - r2.y)),
                       packbf(q2.z * (S1l - r2.z), q2.w * (S1l - r2.w)),
                       packbf(q3.x * (S1l - r3.x), q3.y * (S1l - r3.y)),
                       packbf(q3.z * (S1l - r3.z), q3.w * (S1l - r3.w))};
        B10.u = uint4v{packbf(q0.x * s0.x * 0.5f, q0.y * s0.y * 0.5f),
                       packbf(q0.z * s0.z * 0.5f, q0.w * s0.w * 0.5f),
                       packbf(q1.x * s1.x * 0.5f, q1.y * s1.y * 0.5f),
                       packbf(q1.z * s1.z * 0.5f, q1.w * s1.w * 0.5f)};
        B11.u = uint4v{packbf(q2.x * s2v.x * 0.5f, q2.y * s2v.y * 0.5f),
                       packbf(q2.z * s2v.z * 0.5f, q2.w * s2v.w * 0.5f),
                       packbf(q3.x * s3.x * 0.5f, q3.y * s3.y * 0.5f),
                       packbf(q3.z * s3.z * 0.5f, q3.w * s3.w * 0.5f)};
      } else if (bcol < 110) {                 // S3 columns: B0=dx, B1=0
        const float* dk = dxT + (bcol - 100) * SP;
        f4 q0 = *(const f4*)(dk + lg * 8),      q1 = *(const f4*)(dk + lg * 8 + 4);
        f4 q2 = *(const f4*)(dk + 32 + lg * 8), q3 = *(const f4*)(dk + 32 + lg * 8 + 4);
        B00.u = uint4v{packbf(q0.x, q0.y), packbf(q0.z, q0.w),
                       packbf(q1.x, q1.y), packbf(q1.z, q1.w)};
        B01.u = uint4v{packbf(q2.x, q2.y), packbf(q2.z, q2.w),
                       packbf(q3.x, q3.y), packbf(q3.z, q3.w)};
      }
    }
    __syncthreads();

    // ---- GEMM: wave w owns B column-strip; loop over 7 A row-strips ----
    if (w < 7) {
      const int colbase = w * 16 + lg * 4;     // this lane's 4 output cols
      const short8 zf = {0, 0, 0, 0, 0, 0, 0, 0};
      #pragma unroll 1
      for (int rt = 0; rt < 7; ++rt) {
        const int arow = rt * 16 + lm;
        short8 aV0 = (arow < 100) ? *(const short8*)&Ab[swz(arow, lg * 8)] : zf;
        short8 aV1 = (arow < 100) ? *(const short8*)&Ab[swz(arow, 32 + lg * 8)] : zf;
        short8 aU0 = (arow < 100) ? *(const short8*)&Ub[swz(arow, lg * 8)] : zf;
        short8 aU1 = (arow < 100) ? *(const short8*)&Ub[swz(arow, 32 + lg * 8)] : zf;
        f32x4 acc = {0.f, 0.f, 0.f, 0.f};
        acc = __builtin_amdgcn_mfma_f32_16x16x32_bf16(B00.s, aV0, acc, 0, 0, 0);
        acc = __builtin_amdgcn_mfma_f32_16x16x32_bf16(B01.s, aV1, acc, 0, 0, 0);
        acc = __builtin_amdgcn_mfma_f32_16x16x32_bf16(B10.s, aU0, acc, 0, 0, 0);
        acc = __builtin_amdgcn_mfma_f32_16x16x32_bf16(B11.s, aU1, acc, 0, 0, 0);

        const int row = rt * 16 + lm;          // out row; cols = colbase..+3
        if (row < 100) {
          f2 lo2 = {acc[0], acc[1]};
          f2 hi2 = {acc[2], acc[3]};
          if (colbase < 100) {
            float* rowp4 = ob + 1110 + row * 100;
            *(f2*)(rowp4 + colbase) = lo2;
            *(f2*)(rowp4 + colbase + 2) = hi2;
          } else if (colbase < 110) {          // 100/104/108 -> S3
            float* rowp3 = ob + 110 + row * 10;
            *(f2*)(rowp3 + (colbase - 100)) = lo2;
            if (colbase < 108) *(f2*)(rowp3 + (colbase - 98)) = hi2;
          }
        }
      }
    }
  }
}

extern "C" void kernel_launch(void* const* d_in, const int* in_sizes, int n_in,
                              void* d_out, int out_size, void* d_ws, size_t ws_size,
                              hipStream_t stream) {
  const float* x = (const float*)d_in[0];
  float* out = (float*)d_out;
  const int batch = in_sizes[0] / (C * L);   // 2048
  sig4_kernel<<<dim3(batch / 2), dim3(512), 0, stream>>>(x, out);
}

// Round 29
// 29.168 us; speedup vs baseline: 1.3950x; 1.3950x over previous
//
#include <hip/hip_runtime.h>
#include <hip/hip_bf16.h>

// Depth-4 path signature, C=10, L=64, B=2048 — MFMA formulation (R29 = R27,
// the measured best: 29.1us, absmax 5.25 vs thr 12.16).
// Closed form (validated R8-R27):
//   P_t = exclusive prefix of dx;  R_t[l] = S1[l] - P_{t+1}[l]
//   per (i,j): s2 serial chain; u2_t, v2_t level-2 scalars
//   S4[ij,kl] = sum_t v2_t*(dx_t[k]*R_t[l]) + sum_t u2_t*(dx_t[k]*dx_t[l]/2)
//   S3[ij,k]  = sum_t v2_t*dx_t[k]
// Structure: 512thr/1elem/8waves, TWO barriers.
//  (1) merged stage+scan: each wave loads its channel's 64 path floats from
//      global (coalesced 256B), forms dx via shfl in-register, scans, writes
//      dxT/PsT/P1T in ONE phase (channel map c = 7-w).
//  (2) A-build (t<100, serial s2 chain -> Ab/Ub) runs concurrently with
//      per-lane B-fragment compute (needs only dxT/PsT/P1T); one barrier
//      orders Ab/Ub before the GEMM.
//  (3) GEMM: wave w owns one B column-strip, loops over 7 A row-strips,
//      4 MFMA per strip (V0,V1,U0,U1), transposed-C f2 epilogue.
// LDS 33760B -> 4 blocks/CU under __launch_bounds__(512,8).
// R28 post-mortem: persistent 2-elem loop spilled the B-frag unions to
// scratch (VGPR 32, +45MB scratch traffic each way, 40.7us) — reverted.

typedef short short8 __attribute__((ext_vector_type(8)));
typedef float f2 __attribute__((ext_vector_type(2)));
typedef float f4 __attribute__((ext_vector_type(4)));
typedef float f32x4 __attribute__((ext_vector_type(4)));
typedef unsigned int uint4v __attribute__((ext_vector_type(4)));

constexpr int C = 10, L = 64, T = 63;          // T = L-1 steps
constexpr int OUTSZ = 10 + 100 + 1000 + 10000; // 11110
constexpr int SP = 68;                         // dxT/PsT/P1T row stride (fp32)
constexpr int KS = 64;                         // A row stride in shorts (128B)

__device__ __forceinline__ unsigned packbf(float lo, float hi) {  // v_cvt_pk_bf16_f32
  union { __hip_bfloat162 h; unsigned u; } cv;
  cv.h = __float22bfloat162_rn(make_float2(lo, hi));
  return cv.u;
}
__device__ __forceinline__ int swz(int row, int k) {  // short idx, 16B-granule XOR
  return row * KS + ((((k >> 3) ^ (row & 7)) << 3) | (k & 7));
}
union frag_cast { uint4v u; short8 s; };

__global__ __launch_bounds__(512, 8) void sig4_kernel(
    const float* __restrict__ x, float* __restrict__ out)
{
  __shared__ __align__(16) unsigned char smem_raw[33760];
  unsigned short* Ab = (unsigned short*)smem_raw;            // V2: 12800B
  unsigned short* Ub = (unsigned short*)(smem_raw + 12800);  // U2: 12800B
  float* dxT = (float*)(smem_raw + 25600);                   // 10*68 f = 2720B
  float* PsT = (float*)(smem_raw + 28320);                   // 2720B
  float* P1T = (float*)(smem_raw + 31040);                   // 2720B (P[s+1])

  const int t = threadIdx.x;
  const int w = t >> 6, lane = t & 63;
  const float* __restrict__ xb = x + (size_t)blockIdx.x * (C * L);
  float* __restrict__ ob = out + (size_t)blockIdx.x * OUTSZ;

  // ---- merged stage+scan: one phase, one barrier ----
  for (int c = 7 - w; c < C; c += 8) {       // waves 6,7 take extra channels
    float xv = xb[c * L + lane];             // coalesced 256B per wave
    float xn = __shfl_down(xv, 1);           // x[lane+1]
    float dx = (lane < T) ? (xn - xv) : 0.f; // dx_s = x[s+1]-x[s]
    dxT[c * SP + lane] = dx;
    float vprev = __shfl_up(dx, 1);          // dx[lane-1]
    float v = (lane > 0) ? vprev : 0.f;
    #pragma unroll
    for (int d = 1; d < 64; d <<= 1) {       // inclusive scan of shifted dx = excl
      float y = __shfl_up(v, d);
      if (lane >= d) v += y;
    }
    PsT[c * SP + lane] = v;                  // P[lane]; PsT[63] = S1 (dx63=0)
    float p1 = __shfl_down(v, 1);            // P[lane+1]
    if (lane == 63) p1 = v;
    P1T[c * SP + lane] = p1;
  }
  __syncthreads();

  // ---- A-build (t<100, serial s2 chain) ----
  if (t < 100) {
    const int i_ = t / 10, j_ = t - (t / 10) * 10;
    const float* dip = dxT + i_ * SP;
    const float* pp  = PsT + i_ * SP;
    const float* djp = dxT + j_ * SP;
    float s2 = 0.f;
    #pragma unroll
    for (int ch = 0; ch < 8; ++ch) {
      f4 d0 = *(const f4*)(dip + ch * 8), d1 = *(const f4*)(dip + ch * 8 + 4);
      f4 p0 = *(const f4*)(pp  + ch * 8), p1 = *(const f4*)(pp  + ch * 8 + 4);
      f4 e0 = *(const f4*)(djp + ch * 8), e1 = *(const f4*)(djp + ch * 8 + 4);
      float di[8] = {d0.x, d0.y, d0.z, d0.w, d1.x, d1.y, d1.z, d1.w};
      float pv[8] = {p0.x, p0.y, p0.z, p0.w, p1.x, p1.y, p1.z, p1.w};
      float dj[8] = {e0.x, e0.y, e0.z, e0.w, e1.x, e1.y, e1.z, e1.w};
      float bu[8], bv[8], zz[8];
      #pragma unroll
      for (int e = 0; e < 8; ++e) {            // pointwise (s=63: all zero)
        bu[e] = fmaf(di[e], 0.25f, pv[e]) * (dj[e] * (1.f / 3.f));
        bv[e] = fmaf(di[e], (1.f / 3.f), pv[e]) * (dj[e] * 0.5f);
        zz[e] = fmaf(di[e], 0.5f, pv[e]) * dj[e];
      }
      float u2v[8], v2v[8];
      #pragma unroll
      for (int e = 0; e < 8; ++e) {            // serial: 1 dependent add/step
        u2v[e] = bu[e] + s2;
        v2v[e] = bv[e] + s2;
        s2 += zz[e];
      }
      uint4v vp, up;
      #pragma unroll
      for (int q = 0; q < 4; ++q) {
        vp[q] = packbf(v2v[2 * q], v2v[2 * q + 1]);
        up[q] = packbf(u2v[2 * q], u2v[2 * q + 1]);
      }
      *(uint4v*)&Ab[swz(t, ch * 8)] = vp;
      *(uint4v*)&Ub[swz(t, ch * 8)] = up;
    }
    ob[10 + t] = s2;                           // S2 (fp32)
    if (j_ == 0) ob[i_] = PsT[i_ * SP + 63];   // S1
  }

  // ---- B-fragments: before the barrier (needs only dxT/PsT/P1T) ----
  const int lm = lane & 15, lg = lane >> 4;
  frag_cast B00, B01, B10, B11;
  B00.u = uint4v{0, 0, 0, 0}; B01.u = uint4v{0, 0, 0, 0};
  B10.u = uint4v{0, 0, 0, 0}; B11.u = uint4v{0, 0, 0, 0};
  if (w < 7) {
    const int bcol = w * 16 + lm;              // this lane's B column
    if (bcol < 100) {
      const int k2 = bcol / 10, l2 = bcol - (bcol / 10) * 10;
      const float* dk = dxT + k2 * SP;
      const float* dl = dxT + l2 * SP;
      const float* p1 = P1T + l2 * SP;
      const float S1l = PsT[l2 * SP + 63];
      f4 q0 = *(const f4*)(dk + lg * 8),      q1 = *(const f4*)(dk + lg * 8 + 4);
      f4 q2 = *(const f4*)(dk + 32 + lg * 8), q3 = *(const f4*)(dk + 32 + lg * 8 + 4);
      f4 r0 = *(const f4*)(p1 + lg * 8),      r1 = *(const f4*)(p1 + lg * 8 + 4);
      f4 r2 = *(const f4*)(p1 + 32 + lg * 8), r3 = *(const f4*)(p1 + 32 + lg * 8 + 4);
      f4 s0 = *(const f4*)(dl + lg * 8),      s1 = *(const f4*)(dl + lg * 8 + 4);
      f4 s2v = *(const f4*)(dl + 32 + lg * 8), s3 = *(const f4*)(dl + 32 + lg * 8 + 4);
      B00.u = uint4v{packbf(q0.x * (S1l - r0.x), q0.y * (S1l - r0.y)),
                     packbf(q0.z * (S1l - r0.z), q0.w * (S1l - r0.w)),
                     packbf(q1.x * (S1l - r1.x), q1.y * (S1l - r1.y)),
                     packbf(q1.z * (S1l - r1.z), q1.w * (S1l - r1.w))};
      B01.u = uint4v{packbf(q2.x * (S1l - r2.x), q2.y * (S1l - r2.y)),
                     packbf(q2.z * (S1l - r2.z), q2.w * (S1l - r2.w)),
                     packbf(q3.x * (S1l - r3.x), q3.y * (S1l - r3.y)),
                     packbf(q3.z * (S1l - r3.z), q3.w * (S1l - r3.w))};
      B10.u = uint4v{packbf(q0.x * s0.x * 0.5f, q0.y * s0.y * 0.5f),
                     packbf(q0.z * s0.z * 0.5f, q0.w * s0.w * 0.5f),
                     packbf(q1.x * s1.x * 0.5f, q1.y * s1.y * 0.5f),
                     packbf(q1.z * s1.z * 0.5f, q1.w * s1.w * 0.5f)};
      B11.u = uint4v{packbf(q2.x * s2v.x * 0.5f, q2.y * s2v.y * 0.5f),
                     packbf(q2.z * s2v.z * 0.5f, q2.w * s2v.w * 0.5f),
                     packbf(q3.x * s3.x * 0.5f, q3.y * s3.y * 0.5f),
                     packbf(q3.z * s3.z * 0.5f, q3.w * s3.w * 0.5f)};
    } else if (bcol < 110) {                   // S3 columns: B0=dx, B1=0
      const float* dk = dxT + (bcol - 100) * SP;
      f4 q0 = *(const f4*)(dk + lg * 8),      q1 = *(const f4*)(dk + lg * 8 + 4);
      f4 q2 = *(const f4*)(dk + 32 + lg * 8), q3 = *(const f4*)(dk + 32 + lg * 8 + 4);
      B00.u = uint4v{packbf(q0.x, q0.y), packbf(q0.z, q0.w),
                     packbf(q1.x, q1.y), packbf(q1.z, q1.w)};
      B01.u = uint4v{packbf(q2.x, q2.y), packbf(q2.z, q2.w),
                     packbf(q3.x, q3.y), packbf(q3.z, q3.w)};
    }
  }
  __syncthreads();

  // ---- GEMM: wave w owns B column-strip; loop over 7 A row-strips ----
  if (w < 7) {
    const int colbase = w * 16 + lg * 4;       // this lane's 4 output cols
    const short8 zf = {0, 0, 0, 0, 0, 0, 0, 0};
    #pragma unroll 1
    for (int rt = 0; rt < 7; ++rt) {
      const int arow = rt * 16 + lm;
      short8 aV0 = (arow < 100) ? *(const short8*)&Ab[swz(arow, lg * 8)] : zf;
      short8 aV1 = (arow < 100) ? *(const short8*)&Ab[swz(arow, 32 + lg * 8)] : zf;
      short8 aU0 = (arow < 100) ? *(const short8*)&Ub[swz(arow, lg * 8)] : zf;
      short8 aU1 = (arow < 100) ? *(const short8*)&Ub[swz(arow, 32 + lg * 8)] : zf;
      f32x4 acc = {0.f, 0.f, 0.f, 0.f};
      acc = __builtin_amdgcn_mfma_f32_16x16x32_bf16(B00.s, aV0, acc, 0, 0, 0);
      acc = __builtin_amdgcn_mfma_f32_16x16x32_bf16(B01.s, aV1, acc, 0, 0, 0);
      acc = __builtin_amdgcn_mfma_f32_16x16x32_bf16(B10.s, aU0, acc, 0, 0, 0);
      acc = __builtin_amdgcn_mfma_f32_16x16x32_bf16(B11.s, aU1, acc, 0, 0, 0);

      const int row = rt * 16 + lm;            // out row; cols = colbase..+3
      if (row < 100) {
        f2 lo2 = {acc[0], acc[1]};
        f2 hi2 = {acc[2], acc[3]};
        if (colbase < 100) {
          float* rowp4 = ob + 1110 + row * 100;
          *(f2*)(rowp4 + colbase) = lo2;
          *(f2*)(rowp4 + colbase + 2) = hi2;
        } else if (colbase < 110) {            // 100/104/108 -> S3
          float* rowp3 = ob + 110 + row * 10;
          *(f2*)(rowp3 + (colbase - 100)) = lo2;
          if (colbase < 108) *(f2*)(rowp3 + (colbase - 98)) = hi2;
        }
      }
    }
  }
}

extern "C" void kernel_launch(void* const* d_in, const int* in_sizes, int n_in,
                              void* d_out, int out_size, void* d_ws, size_t ws_size,
                              hipStream_t stream) {
  const float* x = (const float*)d_in[0];
  float* out = (float*)d_out;
  const int batch = in_sizes[0] / (C * L);   // 2048
  sig4_kernel<<<dim3(batch), dim3(512), 0, stream>>>(x, out);
}